// Round 10
// baseline (84.784 us; speedup 1.0000x reference)
//
#include <hip/hip_runtime.h>
#include <hip/hip_bf16.h>

#define POOLED 7
#define PP 49
#define SCALE 0.0625f
#define WMAX 104  // max w-footprint (W=100 + pad); weights zero-filled beyond nw
#define RMAX 20   // max rows per p-bin: bh<=14.4 -> tight support <= 17
#define TW 512    // 8 waves = 4 row-slots x 2 q-halves

// antiderivative of unit hat: Phi(u), Phi(-inf)=0, matches reference _hat_cdf
__device__ __forceinline__ float hat_cdf(float u) {
  if (u <= 0.0f) {
    float t = fminf(fmaxf(u + 1.0f, 0.0f), 1.0f);
    return 0.5f * t * t;
  } else {
    float t = fminf(fmaxf(1.0f - u, 0.0f), 1.0f);
    return 1.0f - 0.5f * t * t;
  }
}

__device__ __forceinline__ float bf_lo(uint32_t u) { return __uint_as_float(u << 16); }
__device__ __forceinline__ float bf_hi(uint32_t u) { return __uint_as_float(u & 0xffff0000u); }

// A[4] += unpack4(U) * WT  (param names must not collide with .x/.y members)
#define FMA4(A, U, WT) do { \
  (A)[0] = fmaf(bf_lo((U).x), (WT), (A)[0]); (A)[1] = fmaf(bf_hi((U).x), (WT), (A)[1]); \
  (A)[2] = fmaf(bf_lo((U).y), (WT), (A)[2]); (A)[3] = fmaf(bf_hi((U).y), (WT), (A)[3]); \
} while (0)

// f32 [B][C][S] -> bf16 [B][S][C]  (S = H*W), coalesced both sides
__global__ __launch_bounds__(256)
void transpose_bf16_kernel(const float* __restrict__ in,
                           __hip_bfloat16* __restrict__ out, int C, int S) {
  __shared__ float tile[32][33];
  int b  = blockIdx.z;
  int s0 = blockIdx.x * 32;
  int c0 = blockIdx.y * 32;
  const float* inb = in + (size_t)b * C * S;
  __hip_bfloat16* outb = out + (size_t)b * S * C;
  int tx = threadIdx.x, ty = threadIdx.y;
#pragma unroll
  for (int j = 0; j < 4; j++) {
    int c = c0 + ty + j * 8, s = s0 + tx;
    tile[ty + j * 8][tx] = (c < C && s < S) ? inb[(size_t)c * S + s] : 0.0f;
  }
  __syncthreads();
#pragma unroll
  for (int j = 0; j < 4; j++) {
    int s = s0 + ty + j * 8, c = c0 + tx;
    if (s < S && c < C) outb[(size_t)s * C + c] = __float2bfloat16(tile[tx][ty + j * 8]);
  }
}

// One 8-wave block per (roi n, bin-row p). wave = (wr, wc): wr=wave&3 takes
// rows round-robin (stride 4, fused pairs (ih, ih+4) -> row-ILP); wc=wave>>2
// takes q-half (0: q0..3, 1: q4..6). Lane owns 4 adjacent channels (uint2 =
// 4 bf16, 512B/wave contiguous). acc = 16 floats/lane, launch_bounds(512,2)
// -> no spill (r7/r8 lesson). NO XCD swizzle: round-9's chunked ROI->XCD
// mapping clustered the heaviest ROIs on single XCDs (occupancy 42%->17%
// across r4->r9); default round-robin dispatch spreads them machine-wide,
// and the 10MB bf16 map is L3-resident so L2 chunk-locality is marginal.
// Single-barrier LDS combine (stride 17, coprime w/ 32 banks), coalesced write.
__global__ __launch_bounds__(TW, 2)
void prroi_kernel(const __hip_bfloat16* __restrict__ ft,
                  const float* __restrict__ rois,
                  float* __restrict__ out, int N, int C, int H, int W) {
  __shared__ float s_wx[POOLED * WMAX];
  __shared__ float s_wy[RMAX];
  __shared__ float s_red[8 * 64 * 17];  // 34,816 B

  int bid = blockIdx.x;
  int n = bid / POOLED;
  int p = bid - n * POOLED;

  int tid = threadIdx.x;
  int wave = tid >> 6, lane = tid & 63;
  int wr = wave & 3;            // row-slot
  int wc = wave >> 2;           // q-half: 0 -> q0..3, 1 -> q4..6
  int qlo = wc ? 4 : 0;
  int qn  = wc ? 3 : 4;

  // uniform roi geometry (broadcast loads)
  float bif = rois[n * 5 + 0];
  float x1  = rois[n * 5 + 1] * SCALE;
  float y1  = rois[n * 5 + 2] * SCALE;
  float x2  = rois[n * 5 + 3] * SCALE;
  float y2  = rois[n * 5 + 4] * SCALE;
  int bi = (int)bif;
  float bw = (x2 - x1) * (1.0f / POOLED);
  float bh = (y2 - y1) * (1.0f / POOLED);
  float ylo = y1 + p * bh, yhi = ylo + bh;

  // tight supports (next cell out has exactly-zero hat weight)
  int w0 = max(0, (int)floorf(x1));
  int w1 = min(W - 1, (int)ceilf(x2));
  int nw = w1 - w0 + 1;
  int h0 = max(0, (int)floorf(ylo));
  int h1 = min(H - 1, (int)ceilf(yhi));
  int rows = h1 - h0 + 1;
  if (rows > RMAX) rows = RMAX;  // cannot trigger here; safety only

  float area = fmaxf(bw * bh, 0.0f);
  float inv_area = (area > 0.0f) ? 1.0f / fmaxf(area, 1e-12f) : 0.0f;

  // x-weights (inv_area folded), zero-filled to WMAX; this p's y-weights
  for (int i = tid; i < POOLED * WMAX; i += TW) {
    int q = i / WMAX, iw = i - q * WMAX;
    float v = 0.0f;
    if (iw < nw) {
      float lo = x1 + q * bw, hi = lo + bw;
      float j = (float)(w0 + iw);
      v = (hat_cdf(hi - j) - hat_cdf(lo - j)) * inv_area;
    }
    s_wx[i] = v;
  }
  for (int i = tid; i < rows; i += TW) {
    float j = (float)(h0 + i);
    s_wy[i] = hat_cdf(yhi - j) - hat_cdf(ylo - j);
  }
  __syncthreads();

  // this wave's per-q tight column ranges (wave-uniform); empty for j >= qn
  int qa[4], qb[4];
#pragma unroll
  for (int j = 0; j < 4; j++) {
    if (j < qn) {
      int q = qlo + j;
      float lo = x1 + q * bw, hi = lo + bw;
      qa[j] = max(0, (int)floorf(lo) - w0);
      qb[j] = min(nw - 1, (int)ceilf(hi) - w0);
    } else {
      qa[j] = 1; qb[j] = 0;  // empty
    }
  }

  float acc[4][4];
#pragma unroll
  for (int j = 0; j < 4; j++)
#pragma unroll
    for (int k = 0; k < 4; k++) acc[j][k] = 0.0f;

  const int C4 = C >> 2;  // uint2 (=4ch) per cell
  const uint2* lp = (const uint2*)ft + ((size_t)bi * H * W) * C4 + lane;

  // rows round-robin over row-slots; fuse pairs (ih, ih+4) for row-ILP
  for (int ih = wr; ih < rows; ih += 8) {
    int iA = ih, iB = ih + 4;
    float wyA = s_wy[iA];
    float wyB = (iB < rows) ? s_wy[iB] : 0.0f;
    if (wyA == 0.0f && wyB == 0.0f) continue;       // wave-uniform
    if (wyA == 0.0f) { wyA = wyB; wyB = 0.0f; iA = iB; }
    bool bOK = (wyB != 0.0f);

    const uint2* rpA = lp + (size_t)((h0 + iA) * W + w0) * C4;
    const uint2* rpB = bOK ? lp + (size_t)((h0 + iB) * W + w0) * C4 : rpA;

#pragma unroll
    for (int j = 0; j < 4; j++) {
      int a = qa[j], b = qb[j];
      const float* wq = s_wx + (qlo + j) * WMAX;
      int iw = a;
      if (bOK) {
        for (; iw + 3 <= b; iw += 4) {  // 8 independent loads in flight
          float wx0 = wq[iw], wx1 = wq[iw + 1], wx2 = wq[iw + 2], wx3 = wq[iw + 3];
          uint2 uA0 = rpA[(size_t)iw * C4];
          uint2 uA1 = rpA[(size_t)(iw + 1) * C4];
          uint2 uA2 = rpA[(size_t)(iw + 2) * C4];
          uint2 uA3 = rpA[(size_t)(iw + 3) * C4];
          uint2 uB0 = rpB[(size_t)iw * C4];
          uint2 uB1 = rpB[(size_t)(iw + 1) * C4];
          uint2 uB2 = rpB[(size_t)(iw + 2) * C4];
          uint2 uB3 = rpB[(size_t)(iw + 3) * C4];
          FMA4(acc[j], uA0, wyA * wx0); FMA4(acc[j], uA1, wyA * wx1);
          FMA4(acc[j], uA2, wyA * wx2); FMA4(acc[j], uA3, wyA * wx3);
          FMA4(acc[j], uB0, wyB * wx0); FMA4(acc[j], uB1, wyB * wx1);
          FMA4(acc[j], uB2, wyB * wx2); FMA4(acc[j], uB3, wyB * wx3);
        }
        for (; iw <= b; iw++) {
          float wx0 = wq[iw];
          uint2 uA = rpA[(size_t)iw * C4];
          uint2 uB = rpB[(size_t)iw * C4];
          FMA4(acc[j], uA, wyA * wx0);
          FMA4(acc[j], uB, wyB * wx0);
        }
      } else {
        for (; iw + 3 <= b; iw += 4) {  // 4 independent loads in flight
          float wx0 = wq[iw], wx1 = wq[iw + 1], wx2 = wq[iw + 2], wx3 = wq[iw + 3];
          uint2 uA0 = rpA[(size_t)iw * C4];
          uint2 uA1 = rpA[(size_t)(iw + 1) * C4];
          uint2 uA2 = rpA[(size_t)(iw + 2) * C4];
          uint2 uA3 = rpA[(size_t)(iw + 3) * C4];
          FMA4(acc[j], uA0, wyA * wx0); FMA4(acc[j], uA1, wyA * wx1);
          FMA4(acc[j], uA2, wyA * wx2); FMA4(acc[j], uA3, wyA * wx3);
        }
        for (; iw <= b; iw++) {
          float wx0 = wq[iw];
          uint2 uA = rpA[(size_t)iw * C4];
          FMA4(acc[j], uA, wyA * wx0);
        }
      }
    }
  }

  // store partials (16 floats/lane) and combine with ONE barrier
  float* slot = s_red + (size_t)(wave * 64 + lane) * 17;
#pragma unroll
  for (int j = 0; j < 4; j++)
#pragma unroll
    for (int k = 0; k < 4; k++) slot[j * 4 + k] = acc[j][k];
  __syncthreads();

  // exclusive slab write: all C channels, bins p*7..p*7+6 (coalesced runs)
  float* oslab = out + (size_t)n * C * PP + p * POOLED;
  const int grpStride = 4 * 64 * 17;  // floats between q-half groups
  for (int i = tid; i < 256 * POOLED; i += TW) {
    int c = i / POOLED, q = i - c * POOLED;
    int grp = (q >= 4) ? 1 : 0;
    int ql = q - (grp << 2);
    int base = grp * grpStride + (c >> 2) * 17 + ql * 4 + (c & 3);
    float v = s_red[base] + s_red[base + 64 * 17] +
              s_red[base + 2 * 64 * 17] + s_red[base + 3 * 64 * 17];
    oslab[(size_t)c * PP + q] = v;
  }
}

// correctness safety net for unexpected shapes / tiny workspace
__global__ void prroi_fallback(const float* __restrict__ feat,
                               const float* __restrict__ rois,
                               float* __restrict__ out, int N, int C, int H, int W) {
  int idx = blockIdx.x * blockDim.x + threadIdx.x;
  if (idx >= N * C * PP) return;
  int n = idx / (C * PP), r = idx % (C * PP);
  int c = r / PP, pq = r % PP;
  int p = pq / POOLED, q = pq % POOLED;
  float x1 = rois[n * 5 + 1] * SCALE, y1 = rois[n * 5 + 2] * SCALE;
  float x2 = rois[n * 5 + 3] * SCALE, y2 = rois[n * 5 + 4] * SCALE;
  int bi = (int)rois[n * 5 + 0];
  float bw = (x2 - x1) / POOLED, bh = (y2 - y1) / POOLED;
  float xlo = x1 + q * bw, xhi = xlo + bw;
  float ylo = y1 + p * bh, yhi = ylo + bh;
  float area = fmaxf(bw * bh, 0.0f);
  float inv_area = (area > 0.0f) ? 1.0f / fmaxf(area, 1e-12f) : 0.0f;
  const float* f = feat + ((size_t)bi * C + c) * H * W;
  float acc = 0.0f;
  int h0 = max(0, (int)floorf(ylo)), h1 = min(H - 1, (int)ceilf(yhi));
  int w0 = max(0, (int)floorf(xlo)), w1 = min(W - 1, (int)ceilf(xhi));
  for (int h = h0; h <= h1; h++) {
    float wy = hat_cdf(yhi - h) - hat_cdf(ylo - h);
    for (int w = w0; w <= w1; w++) {
      float wx = hat_cdf(xhi - w) - hat_cdf(xlo - w);
      acc += f[h * W + w] * wy * wx;
    }
  }
  out[idx] = acc * inv_area;
}

extern "C" void kernel_launch(void* const* d_in, const int* in_sizes, int n_in,
                              void* d_out, int out_size, void* d_ws, size_t ws_size,
                              hipStream_t stream) {
  const float* feat = (const float*)d_in[0];
  const float* rois = (const float*)d_in[1];
  float* out = (float*)d_out;

  const int B = 2, H = 100, W = 100, S = H * W;
  int N = in_sizes[1] / 5;
  int C = out_size / (N * PP);  // 256

  size_t need = (size_t)B * S * C * sizeof(__hip_bfloat16);
  if (C == 256 && ws_size >= need) {
    __hip_bfloat16* ft = (__hip_bfloat16*)d_ws;
    dim3 tb(32, 8);
    dim3 tg((S + 31) / 32, (C + 31) / 32, B);
    transpose_bf16_kernel<<<tg, tb, 0, stream>>>(feat, ft, C, S);
    prroi_kernel<<<N * POOLED, TW, 0, stream>>>(ft, rois, out, N, C, H, W);
  } else {
    int total = N * C * PP;
    prroi_fallback<<<(total + 255) / 256, 256, 0, stream>>>(feat, rois, out, N, C, H, W);
  }
}

// Round 11
// 55.435 us; speedup vs baseline: 1.5294x; 1.5294x over previous
//
#include <hip/hip_runtime.h>
#include <hip/hip_bf16.h>

#define POOLED 7
#define PP 49
#define SCALE 0.0625f
#define WMAX 104  // max w-footprint (W=100 + pad); weights zero-filled beyond nw
#define RMAX 20   // max rows per p-bin: bh<=14.3 -> tight support <= 17
#define TW 256    // 4 waves = 4 row-slots; q-half is split across BLOCKS

// antiderivative of unit hat: Phi(u), Phi(-inf)=0, matches reference _hat_cdf
__device__ __forceinline__ float hat_cdf(float u) {
  if (u <= 0.0f) {
    float t = fminf(fmaxf(u + 1.0f, 0.0f), 1.0f);
    return 0.5f * t * t;
  } else {
    float t = fminf(fmaxf(1.0f - u, 0.0f), 1.0f);
    return 1.0f - 0.5f * t * t;
  }
}

__device__ __forceinline__ float bf_lo(uint32_t u) { return __uint_as_float(u << 16); }
__device__ __forceinline__ float bf_hi(uint32_t u) { return __uint_as_float(u & 0xffff0000u); }

// A[4] += unpack4(U) * WT  (param names must not collide with .x/.y members)
#define FMA4(A, U, WT) do { \
  (A)[0] = fmaf(bf_lo((U).x), (WT), (A)[0]); (A)[1] = fmaf(bf_hi((U).x), (WT), (A)[1]); \
  (A)[2] = fmaf(bf_lo((U).y), (WT), (A)[2]); (A)[3] = fmaf(bf_hi((U).y), (WT), (A)[3]); \
} while (0)

// f32 [B][C][S] -> bf16 [B][S][C]  (S = H*W), coalesced both sides
__global__ __launch_bounds__(256)
void transpose_bf16_kernel(const float* __restrict__ in,
                           __hip_bfloat16* __restrict__ out, int C, int S) {
  __shared__ float tile[32][33];
  int b  = blockIdx.z;
  int s0 = blockIdx.x * 32;
  int c0 = blockIdx.y * 32;
  const float* inb = in + (size_t)b * C * S;
  __hip_bfloat16* outb = out + (size_t)b * S * C;
  int tx = threadIdx.x, ty = threadIdx.y;
#pragma unroll
  for (int j = 0; j < 4; j++) {
    int c = c0 + ty + j * 8, s = s0 + tx;
    tile[ty + j * 8][tx] = (c < C && s < S) ? inb[(size_t)c * S + s] : 0.0f;
  }
  __syncthreads();
#pragma unroll
  for (int j = 0; j < 4; j++) {
    int s = s0 + ty + j * 8, c = c0 + tx;
    if (s < S && c < C) outb[(size_t)s * C + c] = __float2bfloat16(tile[tx][ty + j * 8]);
  }
}

// One 4-wave block per (roi n, bin-row p, q-half). Waves = 4 row-slots taking
// rows round-robin (stride 4, fused pairs (ih, ih+4) -> 8 loads in flight).
// Lane owns 4 adjacent channels (uint2 = 4 bf16, 512B/wave contiguous).
// acc = 16 floats/lane; launch_bounds(256,4) caps VGPR at 128 (need ~70, no
// spill -- r7/r8 lesson: forced occupancy spilled acc = 150+MB scratch traffic).
// Small blocks (19KB LDS) -> 4+ resident blocks/CU to overlap per-block load
// latency (r9 lesson: ~3 resident => CU queues serialize, 17% occupancy).
// Chunked XCD swizzle restored (r9 vs r10 A/B: +10%).
__global__ __launch_bounds__(TW, 4)
void prroi_kernel(const __hip_bfloat16* __restrict__ ft,
                  const float* __restrict__ rois,
                  float* __restrict__ out, int N, int C, int H, int W) {
  __shared__ float s_wx[4 * WMAX];       // this block's (up to) 4 q's
  __shared__ float s_wy[RMAX];
  __shared__ float s_red[4 * 64 * 17];   // 17,408 B; stride 17 coprime w/ 32 banks

  const int PG = POOLED * 2;
  int nb = gridDim.x;
  int bid = blockIdx.x;
  if ((nb & 7) == 0) {
    // chunked XCD swizzle: one ROI's 14 blocks stay on one XCD for L2 reuse
    int cpx = nb >> 3;
    bid = (bid & 7) * cpx + (bid >> 3);
  }
  int n = bid / PG;
  int r = bid - n * PG;
  int p = r >> 1;
  int half = r & 1;
  int qlo = half ? 4 : 0;
  int qn  = half ? 3 : 4;

  int tid = threadIdx.x;
  int wave = tid >> 6, lane = tid & 63;  // wave = row-slot

  // uniform roi geometry (broadcast loads)
  float bif = rois[n * 5 + 0];
  float x1  = rois[n * 5 + 1] * SCALE;
  float y1  = rois[n * 5 + 2] * SCALE;
  float x2  = rois[n * 5 + 3] * SCALE;
  float y2  = rois[n * 5 + 4] * SCALE;
  int bi = (int)bif;
  float bw = (x2 - x1) * (1.0f / POOLED);
  float bh = (y2 - y1) * (1.0f / POOLED);
  float ylo = y1 + p * bh, yhi = ylo + bh;

  // tight supports (next cell out has exactly-zero hat weight)
  int w0 = max(0, (int)floorf(x1));
  int w1 = min(W - 1, (int)ceilf(x2));
  int nw = w1 - w0 + 1;
  int h0 = max(0, (int)floorf(ylo));
  int h1 = min(H - 1, (int)ceilf(yhi));
  int rows = h1 - h0 + 1;
  if (rows > RMAX) rows = RMAX;  // cannot trigger here; safety only

  float area = fmaxf(bw * bh, 0.0f);
  float inv_area = (area > 0.0f) ? 1.0f / fmaxf(area, 1e-12f) : 0.0f;

  // x-weights for this block's q's (inv_area folded), zero beyond nw / q>=7
  for (int i = tid; i < 4 * WMAX; i += TW) {
    int jj = i / WMAX, iw = i - jj * WMAX;
    int q = qlo + jj;
    float v = 0.0f;
    if (iw < nw && q < POOLED) {
      float lo = x1 + q * bw, hi = lo + bw;
      float j = (float)(w0 + iw);
      v = (hat_cdf(hi - j) - hat_cdf(lo - j)) * inv_area;
    }
    s_wx[i] = v;
  }
  for (int i = tid; i < rows; i += TW) {
    float j = (float)(h0 + i);
    s_wy[i] = hat_cdf(yhi - j) - hat_cdf(ylo - j);
  }
  __syncthreads();

  // per-q tight column ranges (wave-uniform); empty for jj >= qn
  int qa[4], qb[4];
#pragma unroll
  for (int jj = 0; jj < 4; jj++) {
    if (jj < qn) {
      int q = qlo + jj;
      float lo = x1 + q * bw, hi = lo + bw;
      qa[jj] = max(0, (int)floorf(lo) - w0);
      qb[jj] = min(nw - 1, (int)ceilf(hi) - w0);
    } else {
      qa[jj] = 1; qb[jj] = 0;  // empty
    }
  }

  float acc[4][4];
#pragma unroll
  for (int jj = 0; jj < 4; jj++)
#pragma unroll
    for (int k = 0; k < 4; k++) acc[jj][k] = 0.0f;

  const int C4 = C >> 2;  // uint2 (=4ch) per cell
  const uint2* lp = (const uint2*)ft + ((size_t)bi * H * W) * C4 + lane;

  // rows round-robin over 4 row-slots; fuse pairs (ih, ih+4) for row-ILP
  for (int ih = wave; ih < rows; ih += 8) {
    int iA = ih, iB = ih + 4;
    float wyA = s_wy[iA];
    float wyB = (iB < rows) ? s_wy[iB] : 0.0f;
    if (wyA == 0.0f && wyB == 0.0f) continue;       // wave-uniform
    if (wyA == 0.0f) { wyA = wyB; wyB = 0.0f; iA = iB; }
    bool bOK = (wyB != 0.0f);

    const uint2* rpA = lp + (size_t)((h0 + iA) * W + w0) * C4;
    const uint2* rpB = bOK ? lp + (size_t)((h0 + iB) * W + w0) * C4 : rpA;

#pragma unroll
    for (int jj = 0; jj < 4; jj++) {
      int a = qa[jj], b = qb[jj];
      const float* wq = s_wx + jj * WMAX;
      int iw = a;
      if (bOK) {
        for (; iw + 3 <= b; iw += 4) {  // 8 independent loads in flight
          float wx0 = wq[iw], wx1 = wq[iw + 1], wx2 = wq[iw + 2], wx3 = wq[iw + 3];
          uint2 uA0 = rpA[(size_t)iw * C4];
          uint2 uA1 = rpA[(size_t)(iw + 1) * C4];
          uint2 uA2 = rpA[(size_t)(iw + 2) * C4];
          uint2 uA3 = rpA[(size_t)(iw + 3) * C4];
          uint2 uB0 = rpB[(size_t)iw * C4];
          uint2 uB1 = rpB[(size_t)(iw + 1) * C4];
          uint2 uB2 = rpB[(size_t)(iw + 2) * C4];
          uint2 uB3 = rpB[(size_t)(iw + 3) * C4];
          FMA4(acc[jj], uA0, wyA * wx0); FMA4(acc[jj], uA1, wyA * wx1);
          FMA4(acc[jj], uA2, wyA * wx2); FMA4(acc[jj], uA3, wyA * wx3);
          FMA4(acc[jj], uB0, wyB * wx0); FMA4(acc[jj], uB1, wyB * wx1);
          FMA4(acc[jj], uB2, wyB * wx2); FMA4(acc[jj], uB3, wyB * wx3);
        }
        for (; iw <= b; iw++) {
          float wx0 = wq[iw];
          uint2 uA = rpA[(size_t)iw * C4];
          uint2 uB = rpB[(size_t)iw * C4];
          FMA4(acc[jj], uA, wyA * wx0);
          FMA4(acc[jj], uB, wyB * wx0);
        }
      } else {
        for (; iw + 3 <= b; iw += 4) {  // 4 independent loads in flight
          float wx0 = wq[iw], wx1 = wq[iw + 1], wx2 = wq[iw + 2], wx3 = wq[iw + 3];
          uint2 uA0 = rpA[(size_t)iw * C4];
          uint2 uA1 = rpA[(size_t)(iw + 1) * C4];
          uint2 uA2 = rpA[(size_t)(iw + 2) * C4];
          uint2 uA3 = rpA[(size_t)(iw + 3) * C4];
          FMA4(acc[jj], uA0, wyA * wx0); FMA4(acc[jj], uA1, wyA * wx1);
          FMA4(acc[jj], uA2, wyA * wx2); FMA4(acc[jj], uA3, wyA * wx3);
        }
        for (; iw <= b; iw++) {
          float wx0 = wq[iw];
          uint2 uA = rpA[(size_t)iw * C4];
          FMA4(acc[jj], uA, wyA * wx0);
        }
      }
    }
  }

  // store partials (16 floats/lane) and combine with ONE barrier
  float* slot = s_red + (size_t)(wave * 64 + lane) * 17;
#pragma unroll
  for (int jj = 0; jj < 4; jj++)
#pragma unroll
    for (int k = 0; k < 4; k++) slot[jj * 4 + k] = acc[jj][k];
  __syncthreads();

  // exclusive write: all C channels, bins q in [qlo, qlo+qn) of bin-row p
  // lane mapping: channel c lived in lane c>>2, slot word jj*4 + (c&3)
  for (int i = tid; i < 256 * 4; i += TW) {
    int c = i >> 2, jj = i & 3;
    if (jj >= qn) continue;
    int base = (c >> 2) * 17 + jj * 4 + (c & 3);
    float v = s_red[base] + s_red[base + 64 * 17] +
              s_red[base + 2 * 64 * 17] + s_red[base + 3 * 64 * 17];
    out[((size_t)n * C + c) * PP + p * POOLED + qlo + jj] = v;
  }
}

// correctness safety net for unexpected shapes / tiny workspace
__global__ void prroi_fallback(const float* __restrict__ feat,
                               const float* __restrict__ rois,
                               float* __restrict__ out, int N, int C, int H, int W) {
  int idx = blockIdx.x * blockDim.x + threadIdx.x;
  if (idx >= N * C * PP) return;
  int n = idx / (C * PP), r = idx % (C * PP);
  int c = r / PP, pq = r % PP;
  int p = pq / POOLED, q = pq % POOLED;
  float x1 = rois[n * 5 + 1] * SCALE, y1 = rois[n * 5 + 2] * SCALE;
  float x2 = rois[n * 5 + 3] * SCALE, y2 = rois[n * 5 + 4] * SCALE;
  int bi = (int)rois[n * 5 + 0];
  float bw = (x2 - x1) / POOLED, bh = (y2 - y1) / POOLED;
  float xlo = x1 + q * bw, xhi = xlo + bw;
  float ylo = y1 + p * bh, yhi = ylo + bh;
  float area = fmaxf(bw * bh, 0.0f);
  float inv_area = (area > 0.0f) ? 1.0f / fmaxf(area, 1e-12f) : 0.0f;
  const float* f = feat + ((size_t)bi * C + c) * H * W;
  float acc = 0.0f;
  int h0 = max(0, (int)floorf(ylo)), h1 = min(H - 1, (int)ceilf(yhi));
  int w0 = max(0, (int)floorf(xlo)), w1 = min(W - 1, (int)ceilf(xhi));
  for (int h = h0; h <= h1; h++) {
    float wy = hat_cdf(yhi - h) - hat_cdf(ylo - h);
    for (int w = w0; w <= w1; w++) {
      float wx = hat_cdf(xhi - w) - hat_cdf(xlo - w);
      acc += f[h * W + w] * wy * wx;
    }
  }
  out[idx] = acc * inv_area;
}

extern "C" void kernel_launch(void* const* d_in, const int* in_sizes, int n_in,
                              void* d_out, int out_size, void* d_ws, size_t ws_size,
                              hipStream_t stream) {
  const float* feat = (const float*)d_in[0];
  const float* rois = (const float*)d_in[1];
  float* out = (float*)d_out;

  const int B = 2, H = 100, W = 100, S = H * W;
  int N = in_sizes[1] / 5;
  int C = out_size / (N * PP);  // 256

  size_t need = (size_t)B * S * C * sizeof(__hip_bfloat16);
  if (C == 256 && ws_size >= need) {
    __hip_bfloat16* ft = (__hip_bfloat16*)d_ws;
    dim3 tb(32, 8);
    dim3 tg((S + 31) / 32, (C + 31) / 32, B);
    transpose_bf16_kernel<<<tg, tb, 0, stream>>>(feat, ft, C, S);
    prroi_kernel<<<N * POOLED * 2, TW, 0, stream>>>(ft, rois, out, N, C, H, W);
  } else {
    int total = N * C * PP;
    prroi_fallback<<<(total + 255) / 256, 256, 0, stream>>>(feat, rois, out, N, C, H, W);
  }
}

// Round 12
// 52.732 us; speedup vs baseline: 1.6078x; 1.0513x over previous
//
#include <hip/hip_runtime.h>
#include <hip/hip_bf16.h>

#define POOLED 7
#define PP 49
#define SCALE 0.0625f
#define RMAX 20   // max rows per p-bin: bh<=14.2 -> tight support <= 17
#define QMAX 24   // max cols per q-bin: bw<=14.2 -> tight support <= 17
#define TW 256    // 4 waves = 4 row-slots

// antiderivative of unit hat: Phi(u), Phi(-inf)=0, matches reference _hat_cdf
__device__ __forceinline__ float hat_cdf(float u) {
  if (u <= 0.0f) {
    float t = fminf(fmaxf(u + 1.0f, 0.0f), 1.0f);
    return 0.5f * t * t;
  } else {
    float t = fminf(fmaxf(1.0f - u, 0.0f), 1.0f);
    return 1.0f - 0.5f * t * t;
  }
}

__device__ __forceinline__ float bf_lo(uint32_t u) { return __uint_as_float(u << 16); }
__device__ __forceinline__ float bf_hi(uint32_t u) { return __uint_as_float(u & 0xffff0000u); }

// A[4] += unpack4(U) * WT  (param names must not collide with .x/.y members)
#define FMA4(A, U, WT) do { \
  (A)[0] = fmaf(bf_lo((U).x), (WT), (A)[0]); (A)[1] = fmaf(bf_hi((U).x), (WT), (A)[1]); \
  (A)[2] = fmaf(bf_lo((U).y), (WT), (A)[2]); (A)[3] = fmaf(bf_hi((U).y), (WT), (A)[3]); \
} while (0)

// f32 [B][C][S] -> bf16 [B][S][C]  (S = H*W), coalesced both sides
__global__ __launch_bounds__(256)
void transpose_bf16_kernel(const float* __restrict__ in,
                           __hip_bfloat16* __restrict__ out, int C, int S) {
  __shared__ float tile[32][33];
  int b  = blockIdx.z;
  int s0 = blockIdx.x * 32;
  int c0 = blockIdx.y * 32;
  const float* inb = in + (size_t)b * C * S;
  __hip_bfloat16* outb = out + (size_t)b * S * C;
  int tx = threadIdx.x, ty = threadIdx.y;
#pragma unroll
  for (int j = 0; j < 4; j++) {
    int c = c0 + ty + j * 8, s = s0 + tx;
    tile[ty + j * 8][tx] = (c < C && s < S) ? inb[(size_t)c * S + s] : 0.0f;
  }
  __syncthreads();
#pragma unroll
  for (int j = 0; j < 4; j++) {
    int s = s0 + ty + j * 8, c = c0 + tx;
    if (s < S && c < C) outb[(size_t)s * C + c] = __float2bfloat16(tile[tx][ty + j * 8]);
  }
}

// One 4-wave block per (roi n, bin p, bin q): finest exclusive-output granule.
// r11 lesson: q-half blocks still left 5-8us heavy stragglers draining a
// mostly-idle machine; single-bin blocks cap worst-block work ~4x lower and
// 12544 blocks keep the dispatcher refilling. Lane owns 4 adjacent channels
// (uint2 = 4 bf16, 512B/wave contiguous). Waves take rows round-robin
// (stride 4, fused pairs (ih, ih+4) -> 8 loads in flight). acc = 4 floats ->
// ~45 VGPR, no spill (r7/r8 lesson); LDS ~6.4KB -> residency wave-limited at
// 8 blocks/CU. Chunked XCD swizzle (r9 vs r10 A/B: +10%) keeps an ROI's 49
// blocks co-XCD so L2 merges the stride-196B partial-line output writes
// (r11: 57MB predicted scatter -> 16MB measured).
__global__ __launch_bounds__(TW, 4)
void prroi_kernel(const __hip_bfloat16* __restrict__ ft,
                  const float* __restrict__ rois,
                  float* __restrict__ out, int N, int C, int H, int W) {
  __shared__ float s_wx[QMAX];
  __shared__ float s_wy[RMAX];
  __shared__ float s_red[4 * 64 * 5];  // 5,120 B; stride 5 coprime w/ 32 banks

  int nb = gridDim.x;
  int bid = blockIdx.x;
  if ((nb & 7) == 0) {
    // chunked XCD swizzle: one ROI's 49 blocks stay on one XCD for L2 reuse
    int cpx = nb >> 3;
    bid = (bid & 7) * cpx + (bid >> 3);
  }
  int n = bid / PP;
  int pq = bid - n * PP;
  int p = pq / POOLED, q = pq - p * POOLED;

  int tid = threadIdx.x;
  int wave = tid >> 6, lane = tid & 63;  // wave = row-slot

  // uniform roi geometry (broadcast loads)
  float bif = rois[n * 5 + 0];
  float x1  = rois[n * 5 + 1] * SCALE;
  float y1  = rois[n * 5 + 2] * SCALE;
  float x2  = rois[n * 5 + 3] * SCALE;
  float y2  = rois[n * 5 + 4] * SCALE;
  int bi = (int)bif;
  float bw = (x2 - x1) * (1.0f / POOLED);
  float bh = (y2 - y1) * (1.0f / POOLED);
  float ylo = y1 + p * bh, yhi = ylo + bh;
  float xlo = x1 + q * bw, xhi = xlo + bw;

  // tight supports (next cell out has exactly-zero hat weight)
  int h0 = max(0, (int)floorf(ylo));
  int h1 = min(H - 1, (int)ceilf(yhi));
  int rows = h1 - h0 + 1;
  if (rows > RMAX) rows = RMAX;  // cannot trigger here; safety only
  int w0 = max(0, (int)floorf(xlo));
  int w1 = min(W - 1, (int)ceilf(xhi));
  int nw = w1 - w0 + 1;
  if (nw > QMAX) nw = QMAX;      // cannot trigger here; safety only

  float area = fmaxf(bw * bh, 0.0f);
  float inv_area = (area > 0.0f) ? 1.0f / fmaxf(area, 1e-12f) : 0.0f;

  // this bin's weights (inv_area folded into wx)
  for (int i = tid; i < nw; i += TW) {
    float j = (float)(w0 + i);
    s_wx[i] = (hat_cdf(xhi - j) - hat_cdf(xlo - j)) * inv_area;
  }
  for (int i = tid; i < rows; i += TW) {
    float j = (float)(h0 + i);
    s_wy[i] = hat_cdf(yhi - j) - hat_cdf(ylo - j);
  }
  __syncthreads();

  float acc[4] = {0.0f, 0.0f, 0.0f, 0.0f};

  const int C4 = C >> 2;  // uint2 (=4ch) per cell
  const uint2* lp = (const uint2*)ft + ((size_t)bi * H * W) * C4 + lane;

  // rows round-robin over 4 row-slots; fuse pairs (ih, ih+4) for 8-deep ILP
  for (int ih = wave; ih < rows; ih += 8) {
    int iA = ih, iB = ih + 4;
    float wyA = s_wy[iA];
    float wyB = (iB < rows) ? s_wy[iB] : 0.0f;
    if (wyA == 0.0f && wyB == 0.0f) continue;       // wave-uniform
    if (wyA == 0.0f) { wyA = wyB; wyB = 0.0f; iA = iB; }
    bool bOK = (wyB != 0.0f);

    const uint2* rpA = lp + (size_t)((h0 + iA) * W + w0) * C4;
    const uint2* rpB = bOK ? lp + (size_t)((h0 + iB) * W + w0) * C4 : rpA;

    int iw = 0;
    if (bOK) {
      for (; iw + 3 < nw; iw += 4) {  // 8 independent loads in flight
        float wx0 = s_wx[iw], wx1 = s_wx[iw + 1], wx2 = s_wx[iw + 2], wx3 = s_wx[iw + 3];
        uint2 uA0 = rpA[(size_t)iw * C4];
        uint2 uA1 = rpA[(size_t)(iw + 1) * C4];
        uint2 uA2 = rpA[(size_t)(iw + 2) * C4];
        uint2 uA3 = rpA[(size_t)(iw + 3) * C4];
        uint2 uB0 = rpB[(size_t)iw * C4];
        uint2 uB1 = rpB[(size_t)(iw + 1) * C4];
        uint2 uB2 = rpB[(size_t)(iw + 2) * C4];
        uint2 uB3 = rpB[(size_t)(iw + 3) * C4];
        FMA4(acc, uA0, wyA * wx0); FMA4(acc, uA1, wyA * wx1);
        FMA4(acc, uA2, wyA * wx2); FMA4(acc, uA3, wyA * wx3);
        FMA4(acc, uB0, wyB * wx0); FMA4(acc, uB1, wyB * wx1);
        FMA4(acc, uB2, wyB * wx2); FMA4(acc, uB3, wyB * wx3);
      }
      for (; iw < nw; iw++) {
        float wx0 = s_wx[iw];
        uint2 uA = rpA[(size_t)iw * C4];
        uint2 uB = rpB[(size_t)iw * C4];
        FMA4(acc, uA, wyA * wx0);
        FMA4(acc, uB, wyB * wx0);
      }
    } else {
      for (; iw + 3 < nw; iw += 4) {  // 4 independent loads in flight
        float wx0 = s_wx[iw], wx1 = s_wx[iw + 1], wx2 = s_wx[iw + 2], wx3 = s_wx[iw + 3];
        uint2 uA0 = rpA[(size_t)iw * C4];
        uint2 uA1 = rpA[(size_t)(iw + 1) * C4];
        uint2 uA2 = rpA[(size_t)(iw + 2) * C4];
        uint2 uA3 = rpA[(size_t)(iw + 3) * C4];
        FMA4(acc, uA0, wyA * wx0); FMA4(acc, uA1, wyA * wx1);
        FMA4(acc, uA2, wyA * wx2); FMA4(acc, uA3, wyA * wx3);
      }
      for (; iw < nw; iw++) {
        float wx0 = s_wx[iw];
        uint2 uA = rpA[(size_t)iw * C4];
        FMA4(acc, uA, wyA * wx0);
      }
    }
  }

  // store partials (4 floats/lane, stride 5 words -> conflict-free), 1 barrier
  float* slot = s_red + (size_t)(wave * 64 + lane) * 5;
#pragma unroll
  for (int k = 0; k < 4; k++) slot[k] = acc[k];
  __syncthreads();

  // combine 4 waves and write: thread tid = channel c (one 4B store each;
  // same-ROI blocks are co-XCD so L2 merges the stride-196B partial lines)
  int c = tid;
  int base = (c >> 2) * 5 + (c & 3);
  float v = s_red[base] + s_red[base + 64 * 5] +
            s_red[base + 2 * 64 * 5] + s_red[base + 3 * 64 * 5];
  out[((size_t)n * C + c) * PP + pq] = v;
}

// correctness safety net for unexpected shapes / tiny workspace
__global__ void prroi_fallback(const float* __restrict__ feat,
                               const float* __restrict__ rois,
                               float* __restrict__ out, int N, int C, int H, int W) {
  int idx = blockIdx.x * blockDim.x + threadIdx.x;
  if (idx >= N * C * PP) return;
  int n = idx / (C * PP), r = idx % (C * PP);
  int c = r / PP, pq = r % PP;
  int p = pq / POOLED, q = pq % POOLED;
  float x1 = rois[n * 5 + 1] * SCALE, y1 = rois[n * 5 + 2] * SCALE;
  float x2 = rois[n * 5 + 3] * SCALE, y2 = rois[n * 5 + 4] * SCALE;
  int bi = (int)rois[n * 5 + 0];
  float bw = (x2 - x1) / POOLED, bh = (y2 - y1) / POOLED;
  float xlo = x1 + q * bw, xhi = xlo + bw;
  float ylo = y1 + p * bh, yhi = ylo + bh;
  float area = fmaxf(bw * bh, 0.0f);
  float inv_area = (area > 0.0f) ? 1.0f / fmaxf(area, 1e-12f) : 0.0f;
  const float* f = feat + ((size_t)bi * C + c) * H * W;
  float acc = 0.0f;
  int h0 = max(0, (int)floorf(ylo)), h1 = min(H - 1, (int)ceilf(yhi));
  int w0 = max(0, (int)floorf(xlo)), w1 = min(W - 1, (int)ceilf(xhi));
  for (int h = h0; h <= h1; h++) {
    float wy = hat_cdf(yhi - h) - hat_cdf(ylo - h);
    for (int w = w0; w <= w1; w++) {
      float wx = hat_cdf(xhi - w) - hat_cdf(xlo - w);
      acc += f[h * W + w] * wy * wx;
    }
  }
  out[idx] = acc * inv_area;
}

extern "C" void kernel_launch(void* const* d_in, const int* in_sizes, int n_in,
                              void* d_out, int out_size, void* d_ws, size_t ws_size,
                              hipStream_t stream) {
  const float* feat = (const float*)d_in[0];
  const float* rois = (const float*)d_in[1];
  float* out = (float*)d_out;

  const int B = 2, H = 100, W = 100, S = H * W;
  int N = in_sizes[1] / 5;
  int C = out_size / (N * PP);  // 256

  size_t need = (size_t)B * S * C * sizeof(__hip_bfloat16);
  if (C == 256 && ws_size >= need) {
    __hip_bfloat16* ft = (__hip_bfloat16*)d_ws;
    dim3 tb(32, 8);
    dim3 tg((S + 31) / 32, (C + 31) / 32, B);
    transpose_bf16_kernel<<<tg, tb, 0, stream>>>(feat, ft, C, S);
    prroi_kernel<<<N * PP, TW, 0, stream>>>(ft, rois, out, N, C, H, W);
  } else {
    int total = N * C * PP;
    prroi_fallback<<<(total + 255) / 256, 256, 0, stream>>>(feat, rois, out, N, C, H, W);
  }
}